// Round 12
// baseline (310.349 us; speedup 1.0000x reference)
//
#include <hip/hip_runtime.h>

typedef unsigned short u16;
typedef short short8 __attribute__((ext_vector_type(8)));
typedef float f32x4 __attribute__((ext_vector_type(4)));

#define AS1C const __attribute__((address_space(1))) void*
#define AS3P __attribute__((address_space(3))) void*
#define VMW(n) asm volatile("s_waitcnt vmcnt(" #n ")" ::: "memory")
#define LGKM0() asm volatile("s_waitcnt lgkmcnt(0)" ::: "memory")
#define SCHEDB() __builtin_amdgcn_sched_barrier(0)

// ---------- bf16 helpers ----------
__device__ __forceinline__ u16 f2b(float f) {
  unsigned u = __float_as_uint(f);
  return (u16)((u + 0x7fffu + ((u >> 16) & 1u)) >> 16);   // RNE
}
__device__ __forceinline__ float b2f(u16 h) {
  return __uint_as_float((unsigned)h << 16);
}

// ---------- problem constants ----------
#define BB 8
#define SS 4096
#define DD 256
#define MTOK (BB*SS)          // 32768 tokens

// ---------- workspace offsets (bytes) ----------
#define OFF_WQKVT  ((size_t)0)           // bf16 [1536][256]
#define OFF_WOT    ((size_t)786432)      // bf16 [256][512]
#define OFF_W1T    ((size_t)1048576)     // bf16 [1024][256]
#define OFF_W2T    ((size_t)1572864)     // bf16 [256][1024]
#define OFF_BQKV   ((size_t)2097152)     // f32  [1536]
#define OFF_XB     ((size_t)2103296)     // bf16 [32768][256]
#define OFF_QKV    ((size_t)18880512)    // bf16 [32768][1536] (V third unused)
#define OFF_YB     ((size_t)52434944)    // bf16 [32768][256]
#define OFF_HB     ((size_t)69212160)    // bf16 [32768][1024]
#define OFF_VT     ((size_t)119543808)   // bf16 [128][256][512]
#define OFF_CTX    ((size_t)153098240)   // bf16 [32768][512]

// ---------------------------------------------------------------------------
// cast_x + prep_w MERGED: prep (257 blocks) hides inside cast's 8192 blocks
// instead of running on an empty machine afterward. Paths are independent.
__global__ __launch_bounds__(256) void cast_prep_kernel(
    const float* __restrict__ x, u16* __restrict__ xb,
    const float* __restrict__ Wq, const float* __restrict__ Wk, const float* __restrict__ Wv,
    const float* __restrict__ Wo, const float* __restrict__ W1, const float* __restrict__ W2,
    const float* __restrict__ bq, const float* __restrict__ bk, const float* __restrict__ bv,
    u16* __restrict__ wqkvt, u16* __restrict__ wot, u16* __restrict__ w1t,
    u16* __restrict__ w2t, float* __restrict__ bqkv)
{
  __shared__ float t[64 * 65];
  const int tid = threadIdx.x;
  if (blockIdx.x < 8192) {                 // ---- cast path ----
    size_t i = ((size_t)blockIdx.x * 256 + tid) * 4;
    float4 v = *(const float4*)(x + i);
    ushort4 o;
    o.x = f2b(v.x); o.y = f2b(v.y); o.z = f2b(v.z); o.w = f2b(v.w);
    *(ushort4*)(xb + i) = o;
    return;
  }
  const int b = blockIdx.x - 8192;         // ---- prep path (257 blocks) ----
  if (b == 256) {                          // bias concat [1536]
    for (int n = tid; n < 1536; n += 256)
      bqkv[n] = (n < 512) ? bq[n] : (n < 1024) ? bk[n - 512] : bv[n - 1024];
    return;
  }
  const float* src; u16* dst; int R, C, tb;
  if (b < 96)       { const int m = b / 32; src = (m == 0) ? Wq : (m == 1) ? Wk : Wv;
                      dst = wqkvt + m * 512 * 256; R = 256; C = 512; tb = b & 31; }
  else if (b < 128) { src = Wo; dst = wot;  R = 512;  C = 256;  tb = b - 96; }
  else if (b < 192) { src = W1; dst = w1t;  R = 256;  C = 1024; tb = b - 128; }
  else              { src = W2; dst = w2t;  R = 1024; C = 256;  tb = b - 192; }
  const int tc = C >> 6;
  const int tr = tb / tc, tcc = tb % tc;
#pragma unroll
  for (int p = 0; p < 16; p++) {
    const int idx = p * 256 + tid, r = idx >> 6, c = idx & 63;
    t[r * 65 + c] = src[(size_t)(tr * 64 + r) * C + tcc * 64 + c];
  }
  __syncthreads();
#pragma unroll
  for (int p = 0; p < 16; p++) {
    const int idx = p * 256 + tid, c = idx >> 6, r = idx & 63;
    dst[(size_t)(tcc * 64 + c) * R + tr * 64 + r] = f2b(t[r * 65 + c]);
  }
}

// ---------------------------------------------------------------------------
// B-resident streaming GEMM v3 (r8, unchanged): 128-col panels, ring-3 A,
// counted vmcnt, one raw barrier/iter.
__global__ __launch_bounds__(256) void gemm_nres(
    const u16* __restrict__ A, const u16* __restrict__ BT,
    const float* __restrict__ bias, u16* __restrict__ C,
    u16* __restrict__ vt, int N, int vbase, int relu)
{
  __shared__ __align__(16) u16 lds[32768];          // 64 KB (B stage / A ring-3)
  const int tid = threadIdx.x, lane = tid & 63, wid = tid >> 6;
  const int ln = lane & 15, quad = lane >> 4;
  const int pn = blockIdx.x >> 6;                   // n-panel (128 cols)
  const int mg = blockIdx.x & 63;                   // m-chunk (512 rows)
  const int wno = (wid >> 1) << 6;                  // 0 / 64
  const int wmo = (wid & 1) << 4;                   // 0 / 16
  const long mbase = (long)mg << 9;
  const int nb = pn << 7;
  const u16* Bp = BT + (size_t)nb * 256;
  const u16* Ap = A + (size_t)mbase * 256;

  // ---- phase 0: stage B panel 128x256 (4096 slots of 16B = 64 KB) ----
#pragma unroll
  for (int p = 0; p < 16; p++) {
    const int s = p * 256 + tid;
    const int row = s >> 5, pc = s & 31;
    const int c = pc ^ (row & 31);
    __builtin_amdgcn_global_load_lds(
        (AS1C)(Bp + (size_t)row * 256 + c * 8), (AS3P)(lds + s * 8), 16, 0, 0);
  }
  __syncthreads();
  short8 breg[4][8];                                // 128 VGPRs
#pragma unroll
  for (int j = 0; j < 4; j++) {
    const int row = wno + j * 16 + ln;
#pragma unroll
    for (int ks = 0; ks < 8; ks++)
      breg[j][ks] = *(const short8*)(lds + row * 256 + (((ks << 2) + quad) ^ (row & 31)) * 8);
  }
  float4 b4h[4];
#pragma unroll
  for (int j = 0; j < 4; j++)
    b4h[j] = *(const float4*)(bias + nb + wno + j * 16 + quad * 4);
  __syncthreads();                                  // B reads done before A overwrites

  // ---- A prologue: slabs 0,1 -> ring 0,1 (4 loads/thread each) ----
#pragma unroll
  for (int sl = 0; sl < 2; sl++) {
    const u16* As = Ap + (size_t)sl * 32 * 256;
#pragma unroll
    for (int p = 0; p < 4; p++) {
      const int s = p * 256 + tid;
      const int row = s >> 5, pc = s & 31;
      const int c = pc ^ (row & 31);
      __builtin_amdgcn_global_load_lds(
          (AS1C)(As + (size_t)row * 256 + c * 8), (AS3P)(lds + sl * 8192 + s * 8), 16, 0, 0);
    }
  }

  for (int it = 0; it < 16; it++) {
    if (it == 0)            VMW(4);
    else if (it == 15)      VMW(0);
    else if (nb < vbase)    VMW(8);
    else                    VMW(20);
    SCHEDB();
    __builtin_amdgcn_s_barrier();
    SCHEDB();
    const u16* Ab = lds + (it % 3) * 8192;
    f32x4 acc[4];
#pragma unroll
    for (int j = 0; j < 4; j++) acc[j] = (f32x4){0.f, 0.f, 0.f, 0.f};
    const int r0 = wmo + ln;
    __builtin_amdgcn_s_setprio(1);
#pragma unroll
    for (int ks = 0; ks < 8; ks++) {
      const short8 a0 = *(const short8*)(Ab + r0 * 256 + (((ks << 2) + quad) ^ (r0 & 31)) * 8);
#pragma unroll
      for (int j = 0; j < 4; j++)
        acc[j] = __builtin_amdgcn_mfma_f32_16x16x32_bf16(breg[j][ks], a0, acc[j], 0, 0, 0);
    }
    __builtin_amdgcn_s_setprio(0);
    // ---- epilogue for this 32-row slab ----
    const long m = mbase + it * 32 + wmo + ln;
    if (nb < vbase) {
#pragma unroll
      for (int j = 0; j < 4; j++) {
        const int n0 = nb + wno + j * 16 + quad * 4;
        f32x4 v = acc[j];
        const float4 b4 = b4h[j];
        v[0] += b4.x; v[1] += b4.y; v[2] += b4.z; v[3] += b4.w;
        if (relu) {
#pragma unroll
          for (int r = 0; r < 4; r++) v[r] = fmaxf(v[r], 0.f);
        }
        ushort4 ob;
        ob.x = f2b(v[0]); ob.y = f2b(v[1]); ob.z = f2b(v[2]); ob.w = f2b(v[3]);
        *(ushort4*)(C + (size_t)m * N + n0) = ob;
      }
    } else {
      // V-panel: write transposed to VT[blk=bw*2+h][k][t]
      const int bw = (int)(m >> 9), t = (int)(m & 511);
#pragma unroll
      for (int j = 0; j < 4; j++) {
        const int n0 = nb + wno + j * 16 + quad * 4;
        const int rel = n0 - vbase;
        const int h = rel >> 8, k0 = rel & 255;
        u16* vp = vt + (size_t)(bw * 2 + h) * 131072 + (size_t)k0 * 512 + t;
        const float4 b4 = b4h[j];
        vp[0]    = f2b(acc[j][0] + b4.x);
        vp[512]  = f2b(acc[j][1] + b4.y);
        vp[1024] = f2b(acc[j][2] + b4.z);
        vp[1536] = f2b(acc[j][3] + b4.w);
      }
    }
    // ---- issue slab it+2 (ring[(it+2)%3] last read iter it-1; barrier separates)
    if (it < 14) {
      const u16* An = Ap + (size_t)(it + 2) * 32 * 256;
      u16* Ax = lds + ((it + 2) % 3) * 8192;
#pragma unroll
      for (int p = 0; p < 4; p++) {
        const int s = p * 256 + tid;
        const int row = s >> 5, pc = s & 31;
        const int c = pc ^ (row & 31);
        __builtin_amdgcn_global_load_lds(
            (AS1C)(An + (size_t)row * 256 + c * 8), (AS3P)(Ax + s * 8), 16, 0, 0);
      }
    }
  }
}

// ---------------------------------------------------------------------------
// FUSED attention v6.1 = v6 with ONE scheduling refinement in the PV loop:
// V_{c+1} is issued right after barrier (A) (dest buf's data V_{c-1} was last
// read before A -> safe), gaining the P-drop + barrier-B window of flight
// time. Barrier (B) becomes raw s_barrier + lgkmcnt(0) (orders the LDS
// P-drop only) -- __syncthreads there would drain the in-flight V_{c+1}.
// Everything else byte-identical to the proven 68.5us v6.
__global__ __launch_bounds__(512, 4) void attn_fused(const u16* __restrict__ qkv,
                                                     const u16* __restrict__ vt,
                                                     u16* __restrict__ ctx)
{
  __shared__ __align__(16) u16 lds[38912];          // 77824 B
  const int tid = threadIdx.x, lane = tid & 63, wid = tid >> 6;
  const int ln = lane & 15, quad = lane >> 4;
  const int bat = blockIdx.x & 127, mt = blockIdx.x >> 7;
  const int bw = bat >> 1, h = bat & 1;
  const u16* Qb = qkv + (size_t)bw * 786432 + (size_t)h * 256 + (size_t)(mt * 64) * 1536;
  const u16* Kb = qkv + (size_t)bw * 786432 + 512 + (size_t)h * 256;
  const u16* Vb = vt + (size_t)bat * 131072;        // [256][512]
  const int wn = wid * 64;
  const int qsw = (ln >> 1) & 3;            // read-side chunk swizzle
  float* red1 = (float*)(lds + 36864);
  float* red2 = red1 + 512;

  // ---- phase 1: S = Q K^T, double-buffered ----
  f32x4 acc[4][4];
#pragma unroll
  for (int i = 0; i < 4; i++)
#pragma unroll
    for (int j = 0; j < 4; j++) acc[i][j] = (f32x4){0.f, 0.f, 0.f, 0.f};

  // prologue: tile 0 -> buf 0 (source chunk-XOR-swizzled, dest linear)
  if (tid < 256) {                          // Q tile: 64x32 = 256 slots
    const int row = tid >> 2;
    const int c = (tid & 3) ^ ((row >> 1) & 3);
    __builtin_amdgcn_global_load_lds(
        (AS1C)(Qb + (size_t)row * 1536 + c * 8), (AS3P)(lds + tid * 8), 16, 0, 0);
  }
#pragma unroll
  for (int p = 0; p < 4; p++) {             // K tile: 512x32 = 2048 slots
    const int s = p * 512 + tid;
    const int row = s >> 2;
    const int c = (s & 3) ^ ((row >> 1) & 3);
    __builtin_amdgcn_global_load_lds(
        (AS1C)(Kb + (size_t)row * 1536 + c * 8), (AS3P)(lds + 4096 + s * 8), 16, 0, 0);
  }

  for (int ki = 0; ki < 8; ki++) {
    const int cur = ki & 1;
    __syncthreads();                        // tile ki arrived; prev reads done
    if (ki < 7) {                           // prefetch tile ki+1 -> other buf
      const int kt = (ki + 1) * 32, nxt = cur ^ 1;
      if (tid < 256) {
        const int row = tid >> 2;
        const int c = (tid & 3) ^ ((row >> 1) & 3);
        __builtin_amdgcn_global_load_lds(
            (AS1C)(Qb + (size_t)row * 1536 + kt + c * 8),
            (AS3P)(lds + nxt * 2048 + tid * 8), 16, 0, 0);
      }
#pragma unroll
      for (int p = 0; p < 4; p++) {
        const int s = p * 512 + tid;
        const int row = s >> 2;
        const int c = (s & 3) ^ ((row >> 1) & 3);
        __builtin_amdgcn_global_load_lds(
            (AS1C)(Kb + (size_t)row * 1536 + kt + c * 8),
            (AS3P)(lds + 4096 + nxt * 16384 + s * 8), 16, 0, 0);
      }
    }
    short8 a[4], b[4];
#pragma unroll
    for (int i = 0; i < 4; i++)
      a[i] = *(const short8*)(lds + cur * 2048 + ((i * 16 + ln) * 4 + (quad ^ qsw)) * 8);
#pragma unroll
    for (int j = 0; j < 4; j++)
      b[j] = *(const short8*)(lds + 4096 + cur * 16384 + ((wn + j * 16 + ln) * 4 + (quad ^ qsw)) * 8);
    __builtin_amdgcn_s_setprio(1);
#pragma unroll
    for (int i = 0; i < 4; i++)
#pragma unroll
      for (int j = 0; j < 4; j++)
        acc[i][j] = __builtin_amdgcn_mfma_f32_16x16x32_bf16(b[j], a[i], acc[i][j], 0, 0, 0);
    __builtin_amdgcn_s_setprio(0);
  }

  // ---- exact softmax over the 512-wide rows ----
  float rowmax[4], rowsum[4];
#pragma unroll
  for (int i = 0; i < 4; i++) {
    float m = -1e30f;
#pragma unroll
    for (int j = 0; j < 4; j++)
#pragma unroll
      for (int r = 0; r < 4; r++) m = fmaxf(m, acc[i][j][r]);
    m = fmaxf(m, __shfl_xor(m, 16));
    m = fmaxf(m, __shfl_xor(m, 32));
    if (quad == 0) red1[wid * 64 + i * 16 + ln] = m;
  }
  __syncthreads();                          // red1 ready (phase-1 LDS now dead)

  // issue V chunk 0 early: covered by the exp pass + sum reduction
#pragma unroll
  for (int p = 0; p < 4; p++) {             // V^T chunk: 256 rows x 128 B
    const int s = p * 512 + tid;
    const int row = s >> 3, pc = s & 7;
    const int cc = pc ^ (row & 7);
    __builtin_amdgcn_global_load_lds(
        (AS1C)(Vb + (size_t)row * 512 + cc * 8), (AS3P)(lds + s * 8), 16, 0, 0);
  }

#pragma unroll
  for (int i = 0; i < 4; i++) {
    float m = -1e30f;
#pragma unroll
    for (int w = 0; w < 8; w++) m = fmaxf(m, red1[w * 64 + i * 16 + ln]);
    rowmax[i] = m;
  }
#pragma unroll
  for (int i = 0; i < 4; i++) {
    float s = 0.f;
#pragma unroll
    for (int j = 0; j < 4; j++)
#pragma unroll
      for (int r = 0; r < 4; r++) {
        const float e = __expf((acc[i][j][r] - rowmax[i]) * 0.0625f); // 1/sqrt(256)
        acc[i][j][r] = e; s += e;
      }
    s += __shfl_xor(s, 16);
    s += __shfl_xor(s, 32);
    if (quad == 0) red2[wid * 64 + i * 16 + ln] = s;
  }
  __syncthreads();                          // red2 ready (also drains V0)
#pragma unroll
  for (int i = 0; i < 4; i++) {
    float s = 0.f;
#pragma unroll
    for (int w = 0; w < 8; w++) s += red2[w * 64 + i * 16 + ln];
    rowsum[i] = 1.f / s;
  }

  // ---- pack P to bf16 regs: acc (64 regs) dies here, pb = 32 regs ----
  ushort4 pb[4][4];
#pragma unroll
  for (int i = 0; i < 4; i++)
#pragma unroll
    for (int j = 0; j < 4; j++) {
      pb[i][j].x = f2b(acc[i][j][0] * rowsum[i]);
      pb[i][j].y = f2b(acc[i][j][1] * rowsum[i]);
      pb[i][j].z = f2b(acc[i][j][2] * rowsum[i]);
      pb[i][j].w = f2b(acc[i][j][3] * rowsum[i]);
    }

  // ---- phase 2: O = P V, double-buffered V chunks ----
  u16* Pb = lds + 32768;                    // 64 x 72 bf16 (9216 B)
  const int wno = wid * 32;
  f32x4 o[4][2];
#pragma unroll
  for (int i = 0; i < 4; i++) {
    o[i][0] = (f32x4){0.f, 0.f, 0.f, 0.f};
    o[i][1] = (f32x4){0.f, 0.f, 0.f, 0.f};
  }

  for (int c = 0; c < 8; c++) {
    __syncthreads();                        // (A) V_c arrived; prev Pb/V reads done
    if (c < 7) {                            // issue V_{c+1} EARLY: dest buf's data
      const int nb = (c + 1) & 1;           // (V_{c-1}) last read before barrier A
#pragma unroll
      for (int p = 0; p < 4; p++) {
        const int s = p * 512 + tid;
        const int row = s >> 3, pc = s & 7;
        const int cc = pc ^ (row & 7);
        __builtin_amdgcn_global_load_lds(
            (AS1C)(Vb + (size_t)row * 512 + (c + 1) * 64 + cc * 8),
            (AS3P)(lds + nb * 16384 + s * 8), 16, 0, 0);
      }
    }
    if (wid == c) {                         // owning wave drops its packed P-slice
#pragma unroll
      for (int i = 0; i < 4; i++)
#pragma unroll
        for (int j = 0; j < 4; j++)
          *(ushort4*)(Pb + (i * 16 + ln) * 72 + j * 16 + quad * 4) = pb[i][j];
    }
    LGKM0();                                // (B) raw: P-drop visible; V_{c+1}
    SCHEDB();                               //     stays in flight (no vmcnt drain)
    __builtin_amdgcn_s_barrier();
    SCHEDB();
    const u16* Vc = lds + (c & 1) * 16384;
    __builtin_amdgcn_s_setprio(1);
#pragma unroll
    for (int ks = 0; ks < 2; ks++) {
      short8 ap[4];
#pragma unroll
      for (int i = 0; i < 4; i++)
        ap[i] = *(const short8*)(Pb + (i * 16 + ln) * 72 + ks * 32 + quad * 8);
#pragma unroll
      for (int j = 0; j < 2; j++) {
        const int kV = wno + j * 16 + ln;
        const short8 bv = *(const short8*)(Vc + kV * 64 + (((ks << 2) + quad) ^ (kV & 7)) * 8);
#pragma unroll
        for (int i = 0; i < 4; i++)
          o[i][j] = __builtin_amdgcn_mfma_f32_16x16x32_bf16(bv, ap[i], o[i][j], 0, 0, 0);
      }
    }
    __builtin_amdgcn_s_setprio(0);
  }

  // ---- epilogue: write CTX rows [bw*512+mt*64 .. +64), cols h*256+wno+.. ----
  const size_t tokr0 = (size_t)bw * 512 + mt * 64;
#pragma unroll
  for (int i = 0; i < 4; i++) {
    const size_t row = tokr0 + i * 16 + ln;
#pragma unroll
    for (int j = 0; j < 2; j++) {
      const int col = h * 256 + wno + j * 16 + quad * 4;
      ushort4 ob;
      ob.x = f2b(o[i][j][0]); ob.y = f2b(o[i][j][1]);
      ob.z = f2b(o[i][j][2]); ob.w = f2b(o[i][j][3]);
      *(ushort4*)(ctx + row * 512 + col) = ob;
    }
  }
}

// ---------------------------------------------------------------------------
// GEMM (N=256) + residual + LayerNorm (r7 ring-3 counted-vmcnt, UNCHANGED).
__global__ __launch_bounds__(256) void gemm_ln(
    const u16* __restrict__ A, const u16* __restrict__ BT,
    const float* __restrict__ bias, const u16* __restrict__ residb,
    const float* __restrict__ g, const float* __restrict__ beta,
    float* __restrict__ yout, u16* __restrict__ ybout, int K)
{
  __shared__ __align__(16) u16 ring[3][10240];   // 3 x 20KB: A[0..2048) B[2048..10240)
  __shared__ float redS[4][64], redQ[4][64];
  const int tid = threadIdx.x, lane = tid & 63, wid = tid >> 6;
  const int ln = lane & 15, quad = lane >> 4;
  const int qsw = (ln >> 1) & 3;
  const long bm = (long)blockIdx.x * 64;
  const int wn = wid * 64;
  const u16* Ab = A + (size_t)bm * K;
  const int nk = K >> 5;

  f32x4 acc[4][4];
#pragma unroll
  for (int i = 0; i < 4; i++)
#pragma unroll
    for (int j = 0; j < 4; j++) acc[i][j] = (f32x4){0.f, 0.f, 0.f, 0.f};

  // prologue: stage steps 0,1 -> ring 0,1 (5 loads/thread each)
#pragma unroll
  for (int sl = 0; sl < 2; sl++) {
    const int kt = sl * 32;
    const int row = tid >> 2;
    const int c = (tid & 3) ^ ((row >> 1) & 3);
    __builtin_amdgcn_global_load_lds(
        (AS1C)(Ab + (size_t)row * K + kt + c * 8), (AS3P)(&ring[sl][0] + tid * 8), 16, 0, 0);
#pragma unroll
    for (int p = 0; p < 4; p++) {
      const int s = p * 256 + tid;
      const int br = s >> 2;
      const int bc = (s & 3) ^ ((br >> 1) & 3);
      __builtin_amdgcn_global_load_lds(
          (AS1C)(BT + (size_t)br * K + kt + bc * 8), (AS3P)(&ring[sl][2048] + s * 8), 16, 0, 0);
    }
  }

  for (int kti = 0; kti < nk; kti++) {
    if (kti + 1 < nk) VMW(5); else VMW(0);
    SCHEDB();
    __builtin_amdgcn_s_barrier();
    SCHEDB();
    const u16* Rc = &ring[kti % 3][0];
    short8 a[4], b[4];
#pragma unroll
    for (int i = 0; i < 4; i++)
      a[i] = *(const short8*)(Rc + ((i * 16 + ln) * 4 + (quad ^ qsw)) * 8);
#pragma unroll
    for (int j = 0; j < 4; j++)
      b[j] = *(const short8*)(Rc + 2048 + ((wn + j * 16 + ln) * 4 + (quad ^ qsw)) * 8);
    __builtin_amdgcn_s_setprio(1);
#pragma unroll
    for (int i = 0; i < 4; i++)
#pragma unroll
      for (int j = 0; j < 4; j++)
        acc[i][j] = __builtin_amdgcn_mfma_f32_16x16x32_bf16(b[j], a[i], acc[i][j], 0, 0, 0);
    __builtin_amdgcn_s_setprio(0);
    // issue step kti+2 (ring[(kti+2)%3] last read iter kti-1; barrier separates)
    if (kti + 2 < nk) {
      const int kt = (kti + 2) * 32;
      u16* Rn = &ring[(kti + 2) % 3][0];
      const int row = tid >> 2;
      const int c = (tid & 3) ^ ((row >> 1) & 3);
      __builtin_amdgcn_global_load_lds(
          (AS1C)(Ab + (size_t)row * K + kt + c * 8), (AS3P)(Rn + tid * 8), 16, 0, 0);
#pragma unroll
      for (int p = 0; p < 4; p++) {
        const int s = p * 256 + tid;
        const int br = s >> 2;
        const int bc = (s & 3) ^ ((br >> 1) & 3);
        __builtin_amdgcn_global_load_lds(
            (AS1C)(BT + (size_t)br * K + kt + bc * 8), (AS3P)(Rn + 2048 + s * 8), 16, 0, 0);
      }
    }
  }

  // ---- epilogue: v = acc + bias + resid; LayerNorm over the 256-row ----
#pragma unroll
  for (int i = 0; i < 4; i++) {
    const long gm = bm + i * 16 + ln;
    float s = 0.f, q = 0.f;
#pragma unroll
    for (int j = 0; j < 4; j++) {
      const int n0 = wn + j * 16 + quad * 4;
      const float4 b4 = *(const float4*)(bias + n0);
      const ushort4 r4 = *(const ushort4*)(residb + (size_t)gm * 256 + n0);
      acc[i][j][0] += b4.x + b2f(r4.x);
      acc[i][j][1] += b4.y + b2f(r4.y);
      acc[i][j][2] += b4.z + b2f(r4.z);
      acc[i][j][3] += b4.w + b2f(r4.w);
#pragma unroll
      for (int r = 0; r < 4; r++) { s += acc[i][j][r]; q += acc[i][j][r] * acc[i][j][r]; }
    }
    s += __shfl_xor(s, 16); s += __shfl_xor(s, 32);
    q += __shfl_xor(q, 16); q += __shfl_xor(q, 32);
    if (quad == 0) { redS[wid][i * 16 + ln] = s; redQ[wid][i * 16 + ln] = q; }
  }
  __syncthreads();
#pragma unroll
  for (int i = 0; i < 4; i++) {
    const long gm = bm + i * 16 + ln;
    float s = 0.f, q = 0.f;
#pragma unroll
    for (int w = 0; w < 4; w++) { s += redS[w][i * 16 + ln]; q += redQ[w][i * 16 + ln]; }
    const float mu = s * (1.f / 256.f);
    const float inv = rsqrtf(q * (1.f / 256.f) - mu * mu + 1e-3f);
#pragma unroll
    for (int j = 0; j < 4; j++) {
      const int n0 = wn + j * 16 + quad * 4;
      const float4 gg = *(const float4*)(g + n0);
      const float4 bb = *(const float4*)(beta + n0);
      float o0 = (acc[i][j][0] - mu) * inv * gg.x + bb.x;
      float o1 = (acc[i][j][1] - mu) * inv * gg.y + bb.y;
      float o2 = (acc[i][j][2] - mu) * inv * gg.z + bb.z;
      float o3 = (acc[i][j][3] - mu) * inv * gg.w + bb.w;
      const size_t off = (size_t)gm * 256 + n0;
      if (yout) {
        float4 o4; o4.x = o0; o4.y = o1; o4.z = o2; o4.w = o3;
        *(float4*)(yout + off) = o4;
      }
      if (ybout) {
        ushort4 ob;
        ob.x = f2b(o0); ob.y = f2b(o1); ob.z = f2b(o2); ob.w = f2b(o3);
        *(ushort4*)(ybout + off) = ob;
      }
    }
  }
}

// ---------------------------------------------------------------------------
extern "C" void kernel_launch(void* const* d_in, const int* in_sizes, int n_in,
                              void* d_out, int out_size, void* d_ws, size_t ws_size,
                              hipStream_t stream) {
  (void)in_sizes; (void)n_in; (void)out_size; (void)ws_size;
  const float* x    = (const float*)d_in[0];
  const float* Wq   = (const float*)d_in[1];
  const float* bq   = (const float*)d_in[2];
  const float* Wk   = (const float*)d_in[3];
  const float* bk   = (const float*)d_in[4];
  const float* Wv   = (const float*)d_in[5];
  const float* bv   = (const float*)d_in[6];
  const float* Wo   = (const float*)d_in[7];
  const float* bo   = (const float*)d_in[8];
  const float* ln1g = (const float*)d_in[9];
  const float* ln1b = (const float*)d_in[10];
  const float* W1   = (const float*)d_in[11];
  const float* b1   = (const float*)d_in[12];
  const float* W2   = (const float*)d_in[13];
  const float* b2   = (const float*)d_in[14];
  const float* ln2g = (const float*)d_in[15];
  const float* ln2b = (const float*)d_in[16];
  float* out = (float*)d_out;

  char* ws = (char*)d_ws;
  u16*   WQKVT = (u16*)(ws + OFF_WQKVT);
  u16*   WOT   = (u16*)(ws + OFF_WOT);
  u16*   W1T   = (u16*)(ws + OFF_W1T);
  u16*   W2T   = (u16*)(ws + OFF_W2T);
  float* BQKV  = (float*)(ws + OFF_BQKV);
  u16*   XB    = (u16*)(ws + OFF_XB);
  u16*   QKV   = (u16*)(ws + OFF_QKV);
  u16*   YB    = (u16*)(ws + OFF_YB);
  u16*   HB    = (u16*)(ws + OFF_HB);
  u16*   VT    = (u16*)(ws + OFF_VT);
  u16*   CTX   = (u16*)(ws + OFF_CTX);

  // cast_x (8192 blocks) + prep_w (257 blocks) merged: prep hides in cast
  cast_prep_kernel<<<8449, 256, 0, stream>>>(x, XB, Wq, Wk, Wv, Wo, W1, W2,
                                             bq, bk, bv, WQKVT, WOT, W1T, W2T, BQKV);
  // QKV projection (128-col panels, 512-row m-chunks): Q,K -> QKV; V -> VT
  gemm_nres<<<768, 256, 0, stream>>>(XB, WQKVT, BQKV, QKV, VT, 1536, 1024, 0);
  // Fused attention v6.1: early V-issue + raw P-barrier
  attn_fused<<<1024, 512, 0, stream>>>(QKV, VT, CTX);
  // attn-out projection + residual(XB) + LN1 -> YB (bf16)
  gemm_ln<<<512, 256, 0, stream>>>(CTX, WOT, bo, XB, ln1g, ln1b, nullptr, YB, 512);
  // FF1 + ReLU (128-col panels): [32768,256] x [256,1024]
  gemm_nres<<<512, 256, 0, stream>>>(YB, W1T, b1, HB, nullptr, 1024, 1 << 30, 1);
  // FF2 + residual(YB) + LN2 -> out (f32)
  gemm_ln<<<512, 256, 0, stream>>>(HB, W2T, b2, YB, ln2g, ln2b, out, nullptr, 1024);
}

// Round 13
// 307.815 us; speedup vs baseline: 1.0082x; 1.0082x over previous
//
#include <hip/hip_runtime.h>

typedef unsigned short u16;
typedef short short8 __attribute__((ext_vector_type(8)));
typedef float f32x4 __attribute__((ext_vector_type(4)));

#define AS1C const __attribute__((address_space(1))) void*
#define AS3P __attribute__((address_space(3))) void*
#define VMW(n) asm volatile("s_waitcnt vmcnt(" #n ")" ::: "memory")
#define SCHEDB() __builtin_amdgcn_sched_barrier(0)

// ---------- bf16 helpers ----------
__device__ __forceinline__ u16 f2b(float f) {
  unsigned u = __float_as_uint(f);
  return (u16)((u + 0x7fffu + ((u >> 16) & 1u)) >> 16);   // RNE
}
__device__ __forceinline__ float b2f(u16 h) {
  return __uint_as_float((unsigned)h << 16);
}

// ---------- problem constants ----------
#define BB 8
#define SS 4096
#define DD 256
#define MTOK (BB*SS)          // 32768 tokens

// ---------- workspace offsets (bytes) ----------
#define OFF_WQKVT  ((size_t)0)           // bf16 [1536][256]
#define OFF_WOT    ((size_t)786432)      // bf16 [256][512]
#define OFF_W1T    ((size_t)1048576)     // bf16 [1024][256]
#define OFF_W2T    ((size_t)1572864)     // bf16 [256][1024]
#define OFF_BQKV   ((size_t)2097152)     // f32  [1536]
#define OFF_XB     ((size_t)2103296)     // bf16 [32768][256]
#define OFF_QKV    ((size_t)18880512)    // bf16 [32768][1536] (V third unused)
#define OFF_YB     ((size_t)52434944)    // bf16 [32768][256]
#define OFF_HB     ((size_t)69212160)    // bf16 [32768][1024]
#define OFF_VT     ((size_t)119543808)   // bf16 [128][256][512]
#define OFF_CTX    ((size_t)153098240)   // bf16 [32768][512]

// ---------------------------------------------------------------------------
// cast_x + prep_w MERGED (r12, retained: ~-3us): prep (257 blocks) hides
// inside cast's 8192 blocks instead of running on an empty machine after.
__global__ __launch_bounds__(256) void cast_prep_kernel(
    const float* __restrict__ x, u16* __restrict__ xb,
    const float* __restrict__ Wq, const float* __restrict__ Wk, const float* __restrict__ Wv,
    const float* __restrict__ Wo, const float* __restrict__ W1, const float* __restrict__ W2,
    const float* __restrict__ bq, const float* __restrict__ bk, const float* __restrict__ bv,
    u16* __restrict__ wqkvt, u16* __restrict__ wot, u16* __restrict__ w1t,
    u16* __restrict__ w2t, float* __restrict__ bqkv)
{
  __shared__ float t[64 * 65];
  const int tid = threadIdx.x;
  if (blockIdx.x < 8192) {                 // ---- cast path ----
    size_t i = ((size_t)blockIdx.x * 256 + tid) * 4;
    float4 v = *(const float4*)(x + i);
    ushort4 o;
    o.x = f2b(v.x); o.y = f2b(v.y); o.z = f2b(v.z); o.w = f2b(v.w);
    *(ushort4*)(xb + i) = o;
    return;
  }
  const int b = blockIdx.x - 8192;         // ---- prep path (257 blocks) ----
  if (b == 256) {                          // bias concat [1536]
    for (int n = tid; n < 1536; n += 256)
      bqkv[n] = (n < 512) ? bq[n] : (n < 1024) ? bk[n - 512] : bv[n - 1024];
    return;
  }
  const float* src; u16* dst; int R, C, tb;
  if (b < 96)       { const int m = b / 32; src = (m == 0) ? Wq : (m == 1) ? Wk : Wv;
                      dst = wqkvt + m * 512 * 256; R = 256; C = 512; tb = b & 31; }
  else if (b < 128) { src = Wo; dst = wot;  R = 512;  C = 256;  tb = b - 96; }
  else if (b < 192) { src = W1; dst = w1t;  R = 256;  C = 1024; tb = b - 128; }
  else              { src = W2; dst = w2t;  R = 1024; C = 256;  tb = b - 192; }
  const int tc = C >> 6;
  const int tr = tb / tc, tcc = tb % tc;
#pragma unroll
  for (int p = 0; p < 16; p++) {
    const int idx = p * 256 + tid, r = idx >> 6, c = idx & 63;
    t[r * 65 + c] = src[(size_t)(tr * 64 + r) * C + tcc * 64 + c];
  }
  __syncthreads();
#pragma unroll
  for (int p = 0; p < 16; p++) {
    const int idx = p * 256 + tid, c = idx >> 6, r = idx & 63;
    dst[(size_t)(tcc * 64 + c) * R + tr * 64 + r] = f2b(t[r * 65 + c]);
  }
}

// ---------------------------------------------------------------------------
// B-resident streaming GEMM v3 (r8, unchanged): 128-col panels, ring-3 A,
// counted vmcnt, one raw barrier/iter.
__global__ __launch_bounds__(256) void gemm_nres(
    const u16* __restrict__ A, const u16* __restrict__ BT,
    const float* __restrict__ bias, u16* __restrict__ C,
    u16* __restrict__ vt, int N, int vbase, int relu)
{
  __shared__ __align__(16) u16 lds[32768];          // 64 KB (B stage / A ring-3)
  const int tid = threadIdx.x, lane = tid & 63, wid = tid >> 6;
  const int ln = lane & 15, quad = lane >> 4;
  const int pn = blockIdx.x >> 6;                   // n-panel (128 cols)
  const int mg = blockIdx.x & 63;                   // m-chunk (512 rows)
  const int wno = (wid >> 1) << 6;                  // 0 / 64
  const int wmo = (wid & 1) << 4;                   // 0 / 16
  const long mbase = (long)mg << 9;
  const int nb = pn << 7;
  const u16* Bp = BT + (size_t)nb * 256;
  const u16* Ap = A + (size_t)mbase * 256;

  // ---- phase 0: stage B panel 128x256 (4096 slots of 16B = 64 KB) ----
#pragma unroll
  for (int p = 0; p < 16; p++) {
    const int s = p * 256 + tid;
    const int row = s >> 5, pc = s & 31;
    const int c = pc ^ (row & 31);
    __builtin_amdgcn_global_load_lds(
        (AS1C)(Bp + (size_t)row * 256 + c * 8), (AS3P)(lds + s * 8), 16, 0, 0);
  }
  __syncthreads();
  short8 breg[4][8];                                // 128 VGPRs
#pragma unroll
  for (int j = 0; j < 4; j++) {
    const int row = wno + j * 16 + ln;
#pragma unroll
    for (int ks = 0; ks < 8; ks++)
      breg[j][ks] = *(const short8*)(lds + row * 256 + (((ks << 2) + quad) ^ (row & 31)) * 8);
  }
  float4 b4h[4];
#pragma unroll
  for (int j = 0; j < 4; j++)
    b4h[j] = *(const float4*)(bias + nb + wno + j * 16 + quad * 4);
  __syncthreads();                                  // B reads done before A overwrites

  // ---- A prologue: slabs 0,1 -> ring 0,1 (4 loads/thread each) ----
#pragma unroll
  for (int sl = 0; sl < 2; sl++) {
    const u16* As = Ap + (size_t)sl * 32 * 256;
#pragma unroll
    for (int p = 0; p < 4; p++) {
      const int s = p * 256 + tid;
      const int row = s >> 5, pc = s & 31;
      const int c = pc ^ (row & 31);
      __builtin_amdgcn_global_load_lds(
          (AS1C)(As + (size_t)row * 256 + c * 8), (AS3P)(lds + sl * 8192 + s * 8), 16, 0, 0);
    }
  }

  for (int it = 0; it < 16; it++) {
    if (it == 0)            VMW(4);
    else if (it == 15)      VMW(0);
    else if (nb < vbase)    VMW(8);
    else                    VMW(20);
    SCHEDB();
    __builtin_amdgcn_s_barrier();
    SCHEDB();
    const u16* Ab = lds + (it % 3) * 8192;
    f32x4 acc[4];
#pragma unroll
    for (int j = 0; j < 4; j++) acc[j] = (f32x4){0.f, 0.f, 0.f, 0.f};
    const int r0 = wmo + ln;
    __builtin_amdgcn_s_setprio(1);
#pragma unroll
    for (int ks = 0; ks < 8; ks++) {
      const short8 a0 = *(const short8*)(Ab + r0 * 256 + (((ks << 2) + quad) ^ (r0 & 31)) * 8);
#pragma unroll
      for (int j = 0; j < 4; j++)
        acc[j] = __builtin_amdgcn_mfma_f32_16x16x32_bf16(breg[j][ks], a0, acc[j], 0, 0, 0);
    }
    __builtin_amdgcn_s_setprio(0);
    // ---- epilogue for this 32-row slab ----
    const long m = mbase + it * 32 + wmo + ln;
    if (nb < vbase) {
#pragma unroll
      for (int j = 0; j < 4; j++) {
        const int n0 = nb + wno + j * 16 + quad * 4;
        f32x4 v = acc[j];
        const float4 b4 = b4h[j];
        v[0] += b4.x; v[1] += b4.y; v[2] += b4.z; v[3] += b4.w;
        if (relu) {
#pragma unroll
          for (int r = 0; r < 4; r++) v[r] = fmaxf(v[r], 0.f);
        }
        ushort4 ob;
        ob.x = f2b(v[0]); ob.y = f2b(v[1]); ob.z = f2b(v[2]); ob.w = f2b(v[3]);
        *(ushort4*)(C + (size_t)m * N + n0) = ob;
      }
    } else {
      // V-panel: write transposed to VT[blk=bw*2+h][k][t]
      const int bw = (int)(m >> 9), t = (int)(m & 511);
#pragma unroll
      for (int j = 0; j < 4; j++) {
        const int n0 = nb + wno + j * 16 + quad * 4;
        const int rel = n0 - vbase;
        const int h = rel >> 8, k0 = rel & 255;
        u16* vp = vt + (size_t)(bw * 2 + h) * 131072 + (size_t)k0 * 512 + t;
        const float4 b4 = b4h[j];
        vp[0]    = f2b(acc[j][0] + b4.x);
        vp[512]  = f2b(acc[j][1] + b4.y);
        vp[1024] = f2b(acc[j][2] + b4.z);
        vp[1536] = f2b(acc[j][3] + b4.w);
      }
    }
    // ---- issue slab it+2 (ring[(it+2)%3] last read iter it-1; barrier separates)
    if (it < 14) {
      const u16* An = Ap + (size_t)(it + 2) * 32 * 256;
      u16* Ax = lds + ((it + 2) % 3) * 8192;
#pragma unroll
      for (int p = 0; p < 4; p++) {
        const int s = p * 256 + tid;
        const int row = s >> 5, pc = s & 31;
        const int c = pc ^ (row & 31);
        __builtin_amdgcn_global_load_lds(
            (AS1C)(An + (size_t)row * 256 + c * 8), (AS3P)(Ax + s * 8), 16, 0, 0);
      }
    }
  }
}

// ---------------------------------------------------------------------------
// FUSED attention v6 (REVERTED byte-identical: proven 68.5-68.8us x3).
// v6.1's early V-issue + raw P-barrier regressed to 74us (MfmaUtil 20->18.4,
// WRITE_SIZE +8MB) -- third confirmation that this PV loop tolerates no
// reordering (v7 ring, v8 fine chunks, v6.1 early-issue all regressed).
__global__ __launch_bounds__(512, 4) void attn_fused(const u16* __restrict__ qkv,
                                                     const u16* __restrict__ vt,
                                                     u16* __restrict__ ctx)
{
  __shared__ __align__(16) u16 lds[38912];          // 77824 B
  const int tid = threadIdx.x, lane = tid & 63, wid = tid >> 6;
  const int ln = lane & 15, quad = lane >> 4;
  const int bat = blockIdx.x & 127, mt = blockIdx.x >> 7;
  const int bw = bat >> 1, h = bat & 1;
  const u16* Qb = qkv + (size_t)bw * 786432 + (size_t)h * 256 + (size_t)(mt * 64) * 1536;
  const u16* Kb = qkv + (size_t)bw * 786432 + 512 + (size_t)h * 256;
  const u16* Vb = vt + (size_t)bat * 131072;        // [256][512]
  const int wn = wid * 64;
  const int qsw = (ln >> 1) & 3;            // read-side chunk swizzle
  float* red1 = (float*)(lds + 36864);
  float* red2 = red1 + 512;

  // ---- phase 1: S = Q K^T, double-buffered ----
  f32x4 acc[4][4];
#pragma unroll
  for (int i = 0; i < 4; i++)
#pragma unroll
    for (int j = 0; j < 4; j++) acc[i][j] = (f32x4){0.f, 0.f, 0.f, 0.f};

  // prologue: tile 0 -> buf 0 (source chunk-XOR-swizzled, dest linear)
  if (tid < 256) {                          // Q tile: 64x32 = 256 slots
    const int row = tid >> 2;
    const int c = (tid & 3) ^ ((row >> 1) & 3);
    __builtin_amdgcn_global_load_lds(
        (AS1C)(Qb + (size_t)row * 1536 + c * 8), (AS3P)(lds + tid * 8), 16, 0, 0);
  }
#pragma unroll
  for (int p = 0; p < 4; p++) {             // K tile: 512x32 = 2048 slots
    const int s = p * 512 + tid;
    const int row = s >> 2;
    const int c = (s & 3) ^ ((row >> 1) & 3);
    __builtin_amdgcn_global_load_lds(
        (AS1C)(Kb + (size_t)row * 1536 + c * 8), (AS3P)(lds + 4096 + s * 8), 16, 0, 0);
  }

  for (int ki = 0; ki < 8; ki++) {
    const int cur = ki & 1;
    __syncthreads();                        // tile ki arrived; prev reads done
    if (ki < 7) {                           // prefetch tile ki+1 -> other buf
      const int kt = (ki + 1) * 32, nxt = cur ^ 1;
      if (tid < 256) {
        const int row = tid >> 2;
        const int c = (tid & 3) ^ ((row >> 1) & 3);
        __builtin_amdgcn_global_load_lds(
            (AS1C)(Qb + (size_t)row * 1536 + kt + c * 8),
            (AS3P)(lds + nxt * 2048 + tid * 8), 16, 0, 0);
      }
#pragma unroll
      for (int p = 0; p < 4; p++) {
        const int s = p * 512 + tid;
        const int row = s >> 2;
        const int c = (s & 3) ^ ((row >> 1) & 3);
        __builtin_amdgcn_global_load_lds(
            (AS1C)(Kb + (size_t)row * 1536 + kt + c * 8),
            (AS3P)(lds + 4096 + nxt * 16384 + s * 8), 16, 0, 0);
      }
    }
    short8 a[4], b[4];
#pragma unroll
    for (int i = 0; i < 4; i++)
      a[i] = *(const short8*)(lds + cur * 2048 + ((i * 16 + ln) * 4 + (quad ^ qsw)) * 8);
#pragma unroll
    for (int j = 0; j < 4; j++)
      b[j] = *(const short8*)(lds + 4096 + cur * 16384 + ((wn + j * 16 + ln) * 4 + (quad ^ qsw)) * 8);
    __builtin_amdgcn_s_setprio(1);
#pragma unroll
    for (int i = 0; i < 4; i++)
#pragma unroll
      for (int j = 0; j < 4; j++)
        acc[i][j] = __builtin_amdgcn_mfma_f32_16x16x32_bf16(b[j], a[i], acc[i][j], 0, 0, 0);
    __builtin_amdgcn_s_setprio(0);
  }

  // ---- exact softmax over the 512-wide rows ----
  float rowmax[4], rowsum[4];
#pragma unroll
  for (int i = 0; i < 4; i++) {
    float m = -1e30f;
#pragma unroll
    for (int j = 0; j < 4; j++)
#pragma unroll
      for (int r = 0; r < 4; r++) m = fmaxf(m, acc[i][j][r]);
    m = fmaxf(m, __shfl_xor(m, 16));
    m = fmaxf(m, __shfl_xor(m, 32));
    if (quad == 0) red1[wid * 64 + i * 16 + ln] = m;
  }
  __syncthreads();                          // red1 ready (phase-1 LDS now dead)

  // issue V chunk 0 early: covered by the exp pass + sum reduction
#pragma unroll
  for (int p = 0; p < 4; p++) {             // V^T chunk: 256 rows x 128 B
    const int s = p * 512 + tid;
    const int row = s >> 3, pc = s & 7;
    const int cc = pc ^ (row & 7);
    __builtin_amdgcn_global_load_lds(
        (AS1C)(Vb + (size_t)row * 512 + cc * 8), (AS3P)(lds + s * 8), 16, 0, 0);
  }

#pragma unroll
  for (int i = 0; i < 4; i++) {
    float m = -1e30f;
#pragma unroll
    for (int w = 0; w < 8; w++) m = fmaxf(m, red1[w * 64 + i * 16 + ln]);
    rowmax[i] = m;
  }
#pragma unroll
  for (int i = 0; i < 4; i++) {
    float s = 0.f;
#pragma unroll
    for (int j = 0; j < 4; j++)
#pragma unroll
      for (int r = 0; r < 4; r++) {
        const float e = __expf((acc[i][j][r] - rowmax[i]) * 0.0625f); // 1/sqrt(256)
        acc[i][j][r] = e; s += e;
      }
    s += __shfl_xor(s, 16);
    s += __shfl_xor(s, 32);
    if (quad == 0) red2[wid * 64 + i * 16 + ln] = s;
  }
  __syncthreads();                          // red2 ready (also drains V0)
#pragma unroll
  for (int i = 0; i < 4; i++) {
    float s = 0.f;
#pragma unroll
    for (int w = 0; w < 8; w++) s += red2[w * 64 + i * 16 + ln];
    rowsum[i] = 1.f / s;
  }

  // ---- pack P to bf16 regs: acc (64 regs) dies here, pb = 32 regs ----
  ushort4 pb[4][4];
#pragma unroll
  for (int i = 0; i < 4; i++)
#pragma unroll
    for (int j = 0; j < 4; j++) {
      pb[i][j].x = f2b(acc[i][j][0] * rowsum[i]);
      pb[i][j].y = f2b(acc[i][j][1] * rowsum[i]);
      pb[i][j].z = f2b(acc[i][j][2] * rowsum[i]);
      pb[i][j].w = f2b(acc[i][j][3] * rowsum[i]);
    }

  // ---- phase 2: O = P V, double-buffered V chunks ----
  u16* Pb = lds + 32768;                    // 64 x 72 bf16 (9216 B)
  const int wno = wid * 32;
  f32x4 o[4][2];
#pragma unroll
  for (int i = 0; i < 4; i++) {
    o[i][0] = (f32x4){0.f, 0.f, 0.f, 0.f};
    o[i][1] = (f32x4){0.f, 0.f, 0.f, 0.f};
  }

  for (int c = 0; c < 8; c++) {
    __syncthreads();                        // (A) V_c arrived; prev Pb/V reads done
    if (wid == c) {                         // owning wave drops its packed P-slice
#pragma unroll
      for (int i = 0; i < 4; i++)
#pragma unroll
        for (int j = 0; j < 4; j++)
          *(ushort4*)(Pb + (i * 16 + ln) * 72 + j * 16 + quad * 4) = pb[i][j];
    }
    __syncthreads();                        // (B) Pbuf ready (cheap: no vmem pending)
    if (c < 7) {                            // prefetch V chunk c+1, covered by MFMAs
      const int nb = (c + 1) & 1;
#pragma unroll
      for (int p = 0; p < 4; p++) {
        const int s = p * 512 + tid;
        const int row = s >> 3, pc = s & 7;
        const int cc = pc ^ (row & 7);
        __builtin_amdgcn_global_load_lds(
            (AS1C)(Vb + (size_t)row * 512 + (c + 1) * 64 + cc * 8),
            (AS3P)(lds + nb * 16384 + s * 8), 16, 0, 0);
      }
    }
    const u16* Vc = lds + (c & 1) * 16384;
    __builtin_amdgcn_s_setprio(1);
#pragma unroll
    for (int ks = 0; ks < 2; ks++) {
      short8 ap[4];
#pragma unroll
      for (int i = 0; i < 4; i++)
        ap[i] = *(const short8*)(Pb + (i * 16 + ln) * 72 + ks * 32 + quad * 8);
#pragma unroll
      for (int j = 0; j < 2; j++) {
        const int kV = wno + j * 16 + ln;
        const short8 bv = *(const short8*)(Vc + kV * 64 + (((ks << 2) + quad) ^ (kV & 7)) * 8);
#pragma unroll
        for (int i = 0; i < 4; i++)
          o[i][j] = __builtin_amdgcn_mfma_f32_16x16x32_bf16(bv, ap[i], o[i][j], 0, 0, 0);
      }
    }
    __builtin_amdgcn_s_setprio(0);
  }

  // ---- epilogue: write CTX rows [bw*512+mt*64 .. +64), cols h*256+wno+.. ----
  const size_t tokr0 = (size_t)bw * 512 + mt * 64;
#pragma unroll
  for (int i = 0; i < 4; i++) {
    const size_t row = tokr0 + i * 16 + ln;
#pragma unroll
    for (int j = 0; j < 2; j++) {
      const int col = h * 256 + wno + j * 16 + quad * 4;
      ushort4 ob;
      ob.x = f2b(o[i][j][0]); ob.y = f2b(o[i][j][1]);
      ob.z = f2b(o[i][j][2]); ob.w = f2b(o[i][j][3]);
      *(ushort4*)(ctx + row * 512 + col) = ob;
    }
  }
}

// ---------------------------------------------------------------------------
// GEMM (N=256) + residual + LayerNorm (r7 ring-3 counted-vmcnt, UNCHANGED).
__global__ __launch_bounds__(256) void gemm_ln(
    const u16* __restrict__ A, const u16* __restrict__ BT,
    const float* __restrict__ bias, const u16* __restrict__ residb,
    const float* __restrict__ g, const float* __restrict__ beta,
    float* __restrict__ yout, u16* __restrict__ ybout, int K)
{
  __shared__ __align__(16) u16 ring[3][10240];   // 3 x 20KB: A[0..2048) B[2048..10240)
  __shared__ float redS[4][64], redQ[4][64];
  const int tid = threadIdx.x, lane = tid & 63, wid = tid >> 6;
  const int ln = lane & 15, quad = lane >> 4;
  const int qsw = (ln >> 1) & 3;
  const long bm = (long)blockIdx.x * 64;
  const int wn = wid * 64;
  const u16* Ab = A + (size_t)bm * K;
  const int nk = K >> 5;

  f32x4 acc[4][4];
#pragma unroll
  for (int i = 0; i < 4; i++)
#pragma unroll
    for (int j = 0; j < 4; j++) acc[i][j] = (f32x4){0.f, 0.f, 0.f, 0.f};

  // prologue: stage steps 0,1 -> ring 0,1 (5 loads/thread each)
#pragma unroll
  for (int sl = 0; sl < 2; sl++) {
    const int kt = sl * 32;
    const int row = tid >> 2;
    const int c = (tid & 3) ^ ((row >> 1) & 3);
    __builtin_amdgcn_global_load_lds(
        (AS1C)(Ab + (size_t)row * K + kt + c * 8), (AS3P)(&ring[sl][0] + tid * 8), 16, 0, 0);
#pragma unroll
    for (int p = 0; p < 4; p++) {
      const int s = p * 256 + tid;
      const int br = s >> 2;
      const int bc = (s & 3) ^ ((br >> 1) & 3);
      __builtin_amdgcn_global_load_lds(
          (AS1C)(BT + (size_t)br * K + kt + bc * 8), (AS3P)(&ring[sl][2048] + s * 8), 16, 0, 0);
    }
  }

  for (int kti = 0; kti < nk; kti++) {
    if (kti + 1 < nk) VMW(5); else VMW(0);
    SCHEDB();
    __builtin_amdgcn_s_barrier();
    SCHEDB();
    const u16* Rc = &ring[kti % 3][0];
    short8 a[4], b[4];
#pragma unroll
    for (int i = 0; i < 4; i++)
      a[i] = *(const short8*)(Rc + ((i * 16 + ln) * 4 + (quad ^ qsw)) * 8);
#pragma unroll
    for (int j = 0; j < 4; j++)
      b[j] = *(const short8*)(Rc + 2048 + ((wn + j * 16 + ln) * 4 + (quad ^ qsw)) * 8);
    __builtin_amdgcn_s_setprio(1);
#pragma unroll
    for (int i = 0; i < 4; i++)
#pragma unroll
      for (int j = 0; j < 4; j++)
        acc[i][j] = __builtin_amdgcn_mfma_f32_16x16x32_bf16(b[j], a[i], acc[i][j], 0, 0, 0);
    __builtin_amdgcn_s_setprio(0);
    // issue step kti+2 (ring[(kti+2)%3] last read iter kti-1; barrier separates)
    if (kti + 2 < nk) {
      const int kt = (kti + 2) * 32;
      u16* Rn = &ring[(kti + 2) % 3][0];
      const int row = tid >> 2;
      const int c = (tid & 3) ^ ((row >> 1) & 3);
      __builtin_amdgcn_global_load_lds(
          (AS1C)(Ab + (size_t)row * K + kt + c * 8), (AS3P)(Rn + tid * 8), 16, 0, 0);
#pragma unroll
      for (int p = 0; p < 4; p++) {
        const int s = p * 256 + tid;
        const int br = s >> 2;
        const int bc = (s & 3) ^ ((br >> 1) & 3);
        __builtin_amdgcn_global_load_lds(
            (AS1C)(BT + (size_t)br * K + kt + bc * 8), (AS3P)(Rn + 2048 + s * 8), 16, 0, 0);
      }
    }
  }

  // ---- epilogue: v = acc + bias + resid; LayerNorm over the 256-row ----
#pragma unroll
  for (int i = 0; i < 4; i++) {
    const long gm = bm + i * 16 + ln;
    float s = 0.f, q = 0.f;
#pragma unroll
    for (int j = 0; j < 4; j++) {
      const int n0 = wn + j * 16 + quad * 4;
      const float4 b4 = *(const float4*)(bias + n0);
      const ushort4 r4 = *(const ushort4*)(residb + (size_t)gm * 256 + n0);
      acc[i][j][0] += b4.x + b2f(r4.x);
      acc[i][j][1] += b4.y + b2f(r4.y);
      acc[i][j][2] += b4.z + b2f(r4.z);
      acc[i][j][3] += b4.w + b2f(r4.w);
#pragma unroll
      for (int r = 0; r < 4; r++) { s += acc[i][j][r]; q += acc[i][j][r] * acc[i][j][r]; }
    }
    s += __shfl_xor(s, 16); s += __shfl_xor(s, 32);
    q += __shfl_xor(q, 16); q += __shfl_xor(q, 32);
    if (quad == 0) { redS[wid][i * 16 + ln] = s; redQ[wid][i * 16 + ln] = q; }
  }
  __syncthreads();
#pragma unroll
  for (int i = 0; i < 4; i++) {
    const long gm = bm + i * 16 + ln;
    float s = 0.f, q = 0.f;
#pragma unroll
    for (int w = 0; w < 4; w++) { s += redS[w][i * 16 + ln]; q += redQ[w][i * 16 + ln]; }
    const float mu = s * (1.f / 256.f);
    const float inv = rsqrtf(q * (1.f / 256.f) - mu * mu + 1e-3f);
#pragma unroll
    for (int j = 0; j < 4; j++) {
      const int n0 = wn + j * 16 + quad * 4;
      const float4 gg = *(const float4*)(g + n0);
      const float4 bb = *(const float4*)(beta + n0);
      float o0 = (acc[i][j][0] - mu) * inv * gg.x + bb.x;
      float o1 = (acc[i][j][1] - mu) * inv * gg.y + bb.y;
      float o2 = (acc[i][j][2] - mu) * inv * gg.z + bb.z;
      float o3 = (acc[i][j][3] - mu) * inv * gg.w + bb.w;
      const size_t off = (size_t)gm * 256 + n0;
      if (yout) {
        float4 o4; o4.x = o0; o4.y = o1; o4.z = o2; o4.w = o3;
        *(float4*)(yout + off) = o4;
      }
      if (ybout) {
        ushort4 ob;
        ob.x = f2b(o0); ob.y = f2b(o1); ob.z = f2b(o2); ob.w = f2b(o3);
        *(ushort4*)(ybout + off) = ob;
      }
    }
  }
}

// ---------------------------------------------------------------------------
extern "C" void kernel_launch(void* const* d_in, const int* in_sizes, int n_in,
                              void* d_out, int out_size, void* d_ws, size_t ws_size,
                              hipStream_t stream) {
  (void)in_sizes; (void)n_in; (void)out_size; (void)ws_size;
  const float* x    = (const float*)d_in[0];
  const float* Wq   = (const float*)d_in[1];
  const float* bq   = (const float*)d_in[2];
  const float* Wk   = (const float*)d_in[3];
  const float* bk   = (const float*)d_in[4];
  const float* Wv   = (const float*)d_in[5];
  const float* bv   = (const float*)d_in[6];
  const float* Wo   = (const float*)d_in[7];
  const float* bo   = (const float*)d_in[8];
  const float* ln1g = (const float*)d_in[9];
  const float* ln1b = (const float*)d_in[10];
  const float* W1   = (const float*)d_in[11];
  const float* b1   = (const float*)d_in[12];
  const float* W2   = (const float*)d_in[13];
  const float* b2   = (const float*)d_in[14];
  const float* ln2g = (const float*)d_in[15];
  const float* ln2b = (const float*)d_in[16];
  float* out = (float*)d_out;

  char* ws = (char*)d_ws;
  u16*   WQKVT = (u16*)(ws + OFF_WQKVT);
  u16*   WOT   = (u16*)(ws + OFF_WOT);
  u16*   W1T   = (u16*)(ws + OFF_W1T);
  u16*   W2T   = (u16*)(ws + OFF_W2T);
  float* BQKV  = (float*)(ws + OFF_BQKV);
  u16*   XB    = (u16*)(ws + OFF_XB);
  u16*   QKV   = (u16*)(ws + OFF_QKV);
  u16*   YB    = (u16*)(ws + OFF_YB);
  u16*   HB    = (u16*)(ws + OFF_HB);
  u16*   VT    = (u16*)(ws + OFF_VT);
  u16*   CTX   = (u16*)(ws + OFF_CTX);

  // cast_x (8192 blocks) + prep_w (257 blocks) merged: prep hides in cast
  cast_prep_kernel<<<8449, 256, 0, stream>>>(x, XB, Wq, Wk, Wv, Wo, W1, W2,
                                             bq, bk, bv, WQKVT, WOT, W1T, W2T, BQKV);
  // QKV projection (128-col panels, 512-row m-chunks): Q,K -> QKV; V -> VT
  gemm_nres<<<768, 256, 0, stream>>>(XB, WQKVT, BQKV, QKV, VT, 1536, 1024, 0);
  // Fused attention v6 (reverted byte-identical: proven 68.5us)
  attn_fused<<<1024, 512, 0, stream>>>(QKV, VT, CTX);
  // attn-out projection + residual(XB) + LN1 -> YB (bf16)
  gemm_ln<<<512, 256, 0, stream>>>(CTX, WOT, bo, XB, ln1g, ln1b, nullptr, YB, 512);
  // FF1 + ReLU (128-col panels): [32768,256] x [256,1024]
  gemm_nres<<<512, 256, 0, stream>>>(YB, W1T, b1, HB, nullptr, 1024, 1 << 30, 1);
  // FF2 + residual(YB) + LN2 -> out (f32)
  gemm_ln<<<512, 256, 0, stream>>>(HB, W2T, b2, YB, ln2g, ln2b, out, nullptr, 1024);
}

// Round 14
// 305.682 us; speedup vs baseline: 1.0153x; 1.0070x over previous
//
#include <hip/hip_runtime.h>

typedef unsigned short u16;
typedef short short8 __attribute__((ext_vector_type(8)));
typedef float f32x4 __attribute__((ext_vector_type(4)));

#define AS1C const __attribute__((address_space(1))) void*
#define AS3P __attribute__((address_space(3))) void*
#define VMW(n) asm volatile("s_waitcnt vmcnt(" #n ")" ::: "memory")
#define SCHEDB() __builtin_amdgcn_sched_barrier(0)

// ---------- bf16 helpers ----------
__device__ __forceinline__ u16 f2b(float f) {
  unsigned u = __float_as_uint(f);
  return (u16)((u + 0x7fffu + ((u >> 16) & 1u)) >> 16);   // RNE
}
__device__ __forceinline__ float b2f(u16 h) {
  return __uint_as_float((unsigned)h << 16);
}

// ---------- problem constants ----------
#define BB 8
#define SS 4096
#define DD 256
#define MTOK (BB*SS)          // 32768 tokens

// ---------- workspace offsets (bytes) ----------
#define OFF_WQKVT  ((size_t)0)           // bf16 [1536][256]
#define OFF_WOT    ((size_t)786432)      // bf16 [256][512]
#define OFF_W1T    ((size_t)1048576)     // bf16 [1024][256]
#define OFF_W2T    ((size_t)1572864)     // bf16 [256][1024]
#define OFF_BQKV   ((size_t)2097152)     // f32  [1536]
#define OFF_XB     ((size_t)2103296)     // bf16 [32768][256]
#define OFF_QKV    ((size_t)18880512)    // bf16 [32768][1536] (V third unused)
#define OFF_YB     ((size_t)52434944)    // bf16 [32768][256]
#define OFF_HB     ((size_t)69212160)    // bf16 [32768][1024]
#define OFF_VT     ((size_t)119543808)   // bf16 [128][256][512]
#define OFF_CTX    ((size_t)153098240)   // bf16 [32768][512]

// ---------------------------------------------------------------------------
// cast_x + prep_w MERGED (r12): prep (257 blocks) hides inside cast's 8192.
__global__ __launch_bounds__(256) void cast_prep_kernel(
    const float* __restrict__ x, u16* __restrict__ xb,
    const float* __restrict__ Wq, const float* __restrict__ Wk, const float* __restrict__ Wv,
    const float* __restrict__ Wo, const float* __restrict__ W1, const float* __restrict__ W2,
    const float* __restrict__ bq, const float* __restrict__ bk, const float* __restrict__ bv,
    u16* __restrict__ wqkvt, u16* __restrict__ wot, u16* __restrict__ w1t,
    u16* __restrict__ w2t, float* __restrict__ bqkv)
{
  __shared__ float t[64 * 65];
  const int tid = threadIdx.x;
  if (blockIdx.x < 8192) {                 // ---- cast path ----
    size_t i = ((size_t)blockIdx.x * 256 + tid) * 4;
    float4 v = *(const float4*)(x + i);
    ushort4 o;
    o.x = f2b(v.x); o.y = f2b(v.y); o.z = f2b(v.z); o.w = f2b(v.w);
    *(ushort4*)(xb + i) = o;
    return;
  }
  const int b = blockIdx.x - 8192;         // ---- prep path (257 blocks) ----
  if (b == 256) {                          // bias concat [1536]
    for (int n = tid; n < 1536; n += 256)
      bqkv[n] = (n < 512) ? bq[n] : (n < 1024) ? bk[n - 512] : bv[n - 1024];
    return;
  }
  const float* src; u16* dst; int R, C, tb;
  if (b < 96)       { const int m = b / 32; src = (m == 0) ? Wq : (m == 1) ? Wk : Wv;
                      dst = wqkvt + m * 512 * 256; R = 256; C = 512; tb = b & 31; }
  else if (b < 128) { src = Wo; dst = wot;  R = 512;  C = 256;  tb = b - 96; }
  else if (b < 192) { src = W1; dst = w1t;  R = 256;  C = 1024; tb = b - 128; }
  else              { src = W2; dst = w2t;  R = 1024; C = 256;  tb = b - 192; }
  const int tc = C >> 6;
  const int tr = tb / tc, tcc = tb % tc;
#pragma unroll
  for (int p = 0; p < 16; p++) {
    const int idx = p * 256 + tid, r = idx >> 6, c = idx & 63;
    t[r * 65 + c] = src[(size_t)(tr * 64 + r) * C + tcc * 64 + c];
  }
  __syncthreads();
#pragma unroll
  for (int p = 0; p < 16; p++) {
    const int idx = p * 256 + tid, c = idx >> 6, r = idx & 63;
    dst[(size_t)(tcc * 64 + c) * R + tr * 64 + r] = f2b(t[r * 65 + c]);
  }
}

// ---------------------------------------------------------------------------
// B-resident streaming GEMM v3 (r8): 128-col panels, ring-3 A, counted vmcnt,
// one raw barrier/iter.
__global__ __launch_bounds__(256) void gemm_nres(
    const u16* __restrict__ A, const u16* __restrict__ BT,
    const float* __restrict__ bias, u16* __restrict__ C,
    u16* __restrict__ vt, int N, int vbase, int relu)
{
  __shared__ __align__(16) u16 lds[32768];          // 64 KB (B stage / A ring-3)
  const int tid = threadIdx.x, lane = tid & 63, wid = tid >> 6;
  const int ln = lane & 15, quad = lane >> 4;
  const int pn = blockIdx.x >> 6;                   // n-panel (128 cols)
  const int mg = blockIdx.x & 63;                   // m-chunk (512 rows)
  const int wno = (wid >> 1) << 6;                  // 0 / 64
  const int wmo = (wid & 1) << 4;                   // 0 / 16
  const long mbase = (long)mg << 9;
  const int nb = pn << 7;
  const u16* Bp = BT + (size_t)nb * 256;
  const u16* Ap = A + (size_t)mbase * 256;

  // ---- phase 0: stage B panel 128x256 (4096 slots of 16B = 64 KB) ----
#pragma unroll
  for (int p = 0; p < 16; p++) {
    const int s = p * 256 + tid;
    const int row = s >> 5, pc = s & 31;
    const int c = pc ^ (row & 31);
    __builtin_amdgcn_global_load_lds(
        (AS1C)(Bp + (size_t)row * 256 + c * 8), (AS3P)(lds + s * 8), 16, 0, 0);
  }
  __syncthreads();
  short8 breg[4][8];                                // 128 VGPRs
#pragma unroll
  for (int j = 0; j < 4; j++) {
    const int row = wno + j * 16 + ln;
#pragma unroll
    for (int ks = 0; ks < 8; ks++)
      breg[j][ks] = *(const short8*)(lds + row * 256 + (((ks << 2) + quad) ^ (row & 31)) * 8);
  }
  float4 b4h[4];
#pragma unroll
  for (int j = 0; j < 4; j++)
    b4h[j] = *(const float4*)(bias + nb + wno + j * 16 + quad * 4);
  __syncthreads();                                  // B reads done before A overwrites

  // ---- A prologue: slabs 0,1 -> ring 0,1 (4 loads/thread each) ----
#pragma unroll
  for (int sl = 0; sl < 2; sl++) {
    const u16* As = Ap + (size_t)sl * 32 * 256;
#pragma unroll
    for (int p = 0; p < 4; p++) {
      const int s = p * 256 + tid;
      const int row = s >> 5, pc = s & 31;
      const int c = pc ^ (row & 31);
      __builtin_amdgcn_global_load_lds(
          (AS1C)(As + (size_t)row * 256 + c * 8), (AS3P)(lds + sl * 8192 + s * 8), 16, 0, 0);
    }
  }

  for (int it = 0; it < 16; it++) {
    if (it == 0)            VMW(4);
    else if (it == 15)      VMW(0);
    else if (nb < vbase)    VMW(8);
    else                    VMW(20);
    SCHEDB();
    __builtin_amdgcn_s_barrier();
    SCHEDB();
    const u16* Ab = lds + (it % 3) * 8192;
    f32x4 acc[4];
#pragma unroll
    for (int j = 0; j < 4; j++) acc[j] = (f32x4){0.f, 0.f, 0.f, 0.f};
    const int r0 = wmo + ln;
    __builtin_amdgcn_s_setprio(1);
#pragma unroll
    for (int ks = 0; ks < 8; ks++) {
      const short8 a0 = *(const short8*)(Ab + r0 * 256 + (((ks << 2) + quad) ^ (r0 & 31)) * 8);
#pragma unroll
      for (int j = 0; j < 4; j++)
        acc[j] = __builtin_amdgcn_mfma_f32_16x16x32_bf16(breg[j][ks], a0, acc[j], 0, 0, 0);
    }
    __builtin_amdgcn_s_setprio(0);
    // ---- epilogue for this 32-row slab ----
    const long m = mbase + it * 32 + wmo + ln;
    if (nb < vbase) {
#pragma unroll
      for (int j = 0; j < 4; j++) {
        const int n0 = nb + wno + j * 16 + quad * 4;
        f32x4 v = acc[j];
        const float4 b4 = b4h[j];
        v[0] += b4.x; v[1] += b4.y; v[2] += b4.z; v[3] += b4.w;
        if (relu) {
#pragma unroll
          for (int r = 0; r < 4; r++) v[r] = fmaxf(v[r], 0.f);
        }
        ushort4 ob;
        ob.x = f2b(v[0]); ob.y = f2b(v[1]); ob.z = f2b(v[2]); ob.w = f2b(v[3]);
        *(ushort4*)(C + (size_t)m * N + n0) = ob;
      }
    } else {
      // V-panel: write transposed to VT[blk=bw*2+h][k][t]
      const int bw = (int)(m >> 9), t = (int)(m & 511);
#pragma unroll
      for (int j = 0; j < 4; j++) {
        const int n0 = nb + wno + j * 16 + quad * 4;
        const int rel = n0 - vbase;
        const int h = rel >> 8, k0 = rel & 255;
        u16* vp = vt + (size_t)(bw * 2 + h) * 131072 + (size_t)k0 * 512 + t;
        const float4 b4 = b4h[j];
        vp[0]    = f2b(acc[j][0] + b4.x);
        vp[512]  = f2b(acc[j][1] + b4.y);
        vp[1024] = f2b(acc[j][2] + b4.z);
        vp[1536] = f2b(acc[j][3] + b4.w);
      }
    }
    // ---- issue slab it+2 (ring[(it+2)%3] last read iter it-1; barrier separates)
    if (it < 14) {
      const u16* An = Ap + (size_t)(it + 2) * 32 * 256;
      u16* Ax = lds + ((it + 2) % 3) * 8192;
#pragma unroll
      for (int p = 0; p < 4; p++) {
        const int s = p * 256 + tid;
        const int row = s >> 5, pc = s & 31;
        const int c = pc ^ (row & 31);
        __builtin_amdgcn_global_load_lds(
            (AS1C)(An + (size_t)row * 256 + c * 8), (AS3P)(Ax + s * 8), 16, 0, 0);
      }
    }
  }
}

// ---------------------------------------------------------------------------
// FUSED attention v6 (final: proven 68.2-68.8us across 5+ dispatg runs).
// Structural minimum for this decomposition: PV ring-3@64col needs 84KB LDS
// (budget 77.8KB @ 2 blocks/CU), phase-1 K ring-3 needs 96KB, 128-row Q
// needs ~190 VGPRs (spill). All reorderings (v3/v5/v6.1/v7/v8) regressed.
__global__ __launch_bounds__(512, 4) void attn_fused(const u16* __restrict__ qkv,
                                                     const u16* __restrict__ vt,
                                                     u16* __restrict__ ctx)
{
  __shared__ __align__(16) u16 lds[38912];          // 77824 B
  const int tid = threadIdx.x, lane = tid & 63, wid = tid >> 6;
  const int ln = lane & 15, quad = lane >> 4;
  const int bat = blockIdx.x & 127, mt = blockIdx.x >> 7;
  const int bw = bat >> 1, h = bat & 1;
  const u16* Qb = qkv + (size_t)bw * 786432 + (size_t)h * 256 + (size_t)(mt * 64) * 1536;
  const u16* Kb = qkv + (size_t)bw * 786432 + 512 + (size_t)h * 256;
  const u16* Vb = vt + (size_t)bat * 131072;        // [256][512]
  const int wn = wid * 64;
  const int qsw = (ln >> 1) & 3;            // read-side chunk swizzle
  float* red1 = (float*)(lds + 36864);
  float* red2 = red1 + 512;

  // ---- phase 1: S = Q K^T, double-buffered ----
  f32x4 acc[4][4];
#pragma unroll
  for (int i = 0; i < 4; i++)
#pragma unroll
    for (int j = 0; j < 4; j++) acc[i][j] = (f32x4){0.f, 0.f, 0.f, 0.f};

  // prologue: tile 0 -> buf 0 (source chunk-XOR-swizzled, dest linear)
  if (tid < 256) {                          // Q tile: 64x32 = 256 slots
    const int row = tid >> 2;
    const int c = (tid & 3) ^ ((row >> 1) & 3);
    __builtin_amdgcn_global_load_lds(
        (AS1C)(Qb + (size_t)row * 1536 + c * 8), (AS3P)(lds + tid * 8), 16, 0, 0);
  }
#pragma unroll
  for (int p = 0; p < 4; p++) {             // K tile: 512x32 = 2048 slots
    const int s = p * 512 + tid;
    const int row = s >> 2;
    const int c = (s & 3) ^ ((row >> 1) & 3);
    __builtin_amdgcn_global_load_lds(
        (AS1C)(Kb + (size_t)row * 1536 + c * 8), (AS3P)(lds + 4096 + s * 8), 16, 0, 0);
  }

  for (int ki = 0; ki < 8; ki++) {
    const int cur = ki & 1;
    __syncthreads();                        // tile ki arrived; prev reads done
    if (ki < 7) {                           // prefetch tile ki+1 -> other buf
      const int kt = (ki + 1) * 32, nxt = cur ^ 1;
      if (tid < 256) {
        const int row = tid >> 2;
        const int c = (tid & 3) ^ ((row >> 1) & 3);
        __builtin_amdgcn_global_load_lds(
            (AS1C)(Qb + (size_t)row * 1536 + kt + c * 8),
            (AS3P)(lds + nxt * 2048 + tid * 8), 16, 0, 0);
      }
#pragma unroll
      for (int p = 0; p < 4; p++) {
        const int s = p * 512 + tid;
        const int row = s >> 2;
        const int c = (s & 3) ^ ((row >> 1) & 3);
        __builtin_amdgcn_global_load_lds(
            (AS1C)(Kb + (size_t)row * 1536 + kt + c * 8),
            (AS3P)(lds + 4096 + nxt * 16384 + s * 8), 16, 0, 0);
      }
    }
    short8 a[4], b[4];
#pragma unroll
    for (int i = 0; i < 4; i++)
      a[i] = *(const short8*)(lds + cur * 2048 + ((i * 16 + ln) * 4 + (quad ^ qsw)) * 8);
#pragma unroll
    for (int j = 0; j < 4; j++)
      b[j] = *(const short8*)(lds + 4096 + cur * 16384 + ((wn + j * 16 + ln) * 4 + (quad ^ qsw)) * 8);
    __builtin_amdgcn_s_setprio(1);
#pragma unroll
    for (int i = 0; i < 4; i++)
#pragma unroll
      for (int j = 0; j < 4; j++)
        acc[i][j] = __builtin_amdgcn_mfma_f32_16x16x32_bf16(b[j], a[i], acc[i][j], 0, 0, 0);
    __builtin_amdgcn_s_setprio(0);
  }

  // ---- exact softmax over the 512-wide rows ----
  float rowmax[4], rowsum[4];
#pragma unroll
  for (int i = 0; i < 4; i++) {
    float m = -1e30f;
#pragma unroll
    for (int j = 0; j < 4; j++)
#pragma unroll
      for (int r = 0; r < 4; r++) m = fmaxf(m, acc[i][j][r]);
    m = fmaxf(m, __shfl_xor(m, 16));
    m = fmaxf(m, __shfl_xor(m, 32));
    if (quad == 0) red1[wid * 64 + i * 16 + ln] = m;
  }
  __syncthreads();                          // red1 ready (phase-1 LDS now dead)

  // issue V chunk 0 early: covered by the exp pass + sum reduction
#pragma unroll
  for (int p = 0; p < 4; p++) {             // V^T chunk: 256 rows x 128 B
    const int s = p * 512 + tid;
    const int row = s >> 3, pc = s & 7;
    const int cc = pc ^ (row & 7);
    __builtin_amdgcn_global_load_lds(
        (AS1C)(Vb + (size_t)row * 512 + cc * 8), (AS3P)(lds + s * 8), 16, 0, 0);
  }

#pragma unroll
  for (int i = 0; i < 4; i++) {
    float m = -1e30f;
#pragma unroll
    for (int w = 0; w < 8; w++) m = fmaxf(m, red1[w * 64 + i * 16 + ln]);
    rowmax[i] = m;
  }
#pragma unroll
  for (int i = 0; i < 4; i++) {
    float s = 0.f;
#pragma unroll
    for (int j = 0; j < 4; j++)
#pragma unroll
      for (int r = 0; r < 4; r++) {
        const float e = __expf((acc[i][j][r] - rowmax[i]) * 0.0625f); // 1/sqrt(256)
        acc[i][j][r] = e; s += e;
      }
    s += __shfl_xor(s, 16);
    s += __shfl_xor(s, 32);
    if (quad == 0) red2[wid * 64 + i * 16 + ln] = s;
  }
  __syncthreads();                          // red2 ready (also drains V0)
#pragma unroll
  for (int i = 0; i < 4; i++) {
    float s = 0.f;
#pragma unroll
    for (int w = 0; w < 8; w++) s += red2[w * 64 + i * 16 + ln];
    rowsum[i] = 1.f / s;
  }

  // ---- pack P to bf16 regs: acc (64 regs) dies here, pb = 32 regs ----
  ushort4 pb[4][4];
#pragma unroll
  for (int i = 0; i < 4; i++)
#pragma unroll
    for (int j = 0; j < 4; j++) {
      pb[i][j].x = f2b(acc[i][j][0] * rowsum[i]);
      pb[i][j].y = f2b(acc[i][j][1] * rowsum[i]);
      pb[i][j].z = f2b(acc[i][j][2] * rowsum[i]);
      pb[i][j].w = f2b(acc[i][j][3] * rowsum[i]);
    }

  // ---- phase 2: O = P V, double-buffered V chunks ----
  u16* Pb = lds + 32768;                    // 64 x 72 bf16 (9216 B)
  const int wno = wid * 32;
  f32x4 o[4][2];
#pragma unroll
  for (int i = 0; i < 4; i++) {
    o[i][0] = (f32x4){0.f, 0.f, 0.f, 0.f};
    o[i][1] = (f32x4){0.f, 0.f, 0.f, 0.f};
  }

  for (int c = 0; c < 8; c++) {
    __syncthreads();                        // (A) V_c arrived; prev Pb/V reads done
    if (wid == c) {                         // owning wave drops its packed P-slice
#pragma unroll
      for (int i = 0; i < 4; i++)
#pragma unroll
        for (int j = 0; j < 4; j++)
          *(ushort4*)(Pb + (i * 16 + ln) * 72 + j * 16 + quad * 4) = pb[i][j];
    }
    __syncthreads();                        // (B) Pbuf ready (cheap: no vmem pending)
    if (c < 7) {                            // prefetch V chunk c+1, covered by MFMAs
      const int nb = (c + 1) & 1;
#pragma unroll
      for (int p = 0; p < 4; p++) {
        const int s = p * 512 + tid;
        const int row = s >> 3, pc = s & 7;
        const int cc = pc ^ (row & 7);
        __builtin_amdgcn_global_load_lds(
            (AS1C)(Vb + (size_t)row * 512 + (c + 1) * 64 + cc * 8),
            (AS3P)(lds + nb * 16384 + s * 8), 16, 0, 0);
      }
    }
    const u16* Vc = lds + (c & 1) * 16384;
    __builtin_amdgcn_s_setprio(1);
#pragma unroll
    for (int ks = 0; ks < 2; ks++) {
      short8 ap[4];
#pragma unroll
      for (int i = 0; i < 4; i++)
        ap[i] = *(const short8*)(Pb + (i * 16 + ln) * 72 + ks * 32 + quad * 8);
#pragma unroll
      for (int j = 0; j < 2; j++) {
        const int kV = wno + j * 16 + ln;
        const short8 bv = *(const short8*)(Vc + kV * 64 + (((ks << 2) + quad) ^ (kV & 7)) * 8);
#pragma unroll
        for (int i = 0; i < 4; i++)
          o[i][j] = __builtin_amdgcn_mfma_f32_16x16x32_bf16(bv, ap[i], o[i][j], 0, 0, 0);
      }
    }
    __builtin_amdgcn_s_setprio(0);
  }

  // ---- epilogue: write CTX rows [bw*512+mt*64 .. +64), cols h*256+wno+.. ----
  const size_t tokr0 = (size_t)bw * 512 + mt * 64;
#pragma unroll
  for (int i = 0; i < 4; i++) {
    const size_t row = tokr0 + i * 16 + ln;
#pragma unroll
    for (int j = 0; j < 2; j++) {
      const int col = h * 256 + wno + j * 16 + quad * 4;
      ushort4 ob;
      ob.x = f2b(o[i][j][0]); ob.y = f2b(o[i][j][1]);
      ob.z = f2b(o[i][j][2]); ob.w = f2b(o[i][j][3]);
      *(ushort4*)(ctx + row * 512 + col) = ob;
    }
  }
}

// ---------------------------------------------------------------------------
// GEMM (N=256) + residual + LayerNorm (r7 ring-3 counted-vmcnt).
__global__ __launch_bounds__(256) void gemm_ln(
    const u16* __restrict__ A, const u16* __restrict__ BT,
    const float* __restrict__ bias, const u16* __restrict__ residb,
    const float* __restrict__ g, const float* __restrict__ beta,
    float* __restrict__ yout, u16* __restrict__ ybout, int K)
{
  __shared__ __align__(16) u16 ring[3][10240];   // 3 x 20KB: A[0..2048) B[2048..10240)
  __shared__ float redS[4][64], redQ[4][64];
  const int tid = threadIdx.x, lane = tid & 63, wid = tid >> 6;
  const int ln = lane & 15, quad = lane >> 4;
  const int qsw = (ln >> 1) & 3;
  const long bm = (long)blockIdx.x * 64;
  const int wn = wid * 64;
  const u16* Ab = A + (size_t)bm * K;
  const int nk = K >> 5;

  f32x4 acc[4][4];
#pragma unroll
  for (int i = 0; i < 4; i++)
#pragma unroll
    for (int j = 0; j < 4; j++) acc[i][j] = (f32x4){0.f, 0.f, 0.f, 0.f};

  // prologue: stage steps 0,1 -> ring 0,1 (5 loads/thread each)
#pragma unroll
  for (int sl = 0; sl < 2; sl++) {
    const int kt = sl * 32;
    const int row = tid >> 2;
    const int c = (tid & 3) ^ ((row >> 1) & 3);
    __builtin_amdgcn_global_load_lds(
        (AS1C)(Ab + (size_t)row * K + kt + c * 8), (AS3P)(&ring[sl][0] + tid * 8), 16, 0, 0);
#pragma unroll
    for (int p = 0; p < 4; p++) {
      const int s = p * 256 + tid;
      const int br = s >> 2;
      const int bc = (s & 3) ^ ((br >> 1) & 3);
      __builtin_amdgcn_global_load_lds(
          (AS1C)(BT + (size_t)br * K + kt + bc * 8), (AS3P)(&ring[sl][2048] + s * 8), 16, 0, 0);
    }
  }

  for (int kti = 0; kti < nk; kti++) {
    if (kti + 1 < nk) VMW(5); else VMW(0);
    SCHEDB();
    __builtin_amdgcn_s_barrier();
    SCHEDB();
    const u16* Rc = &ring[kti % 3][0];
    short8 a[4], b[4];
#pragma unroll
    for (int i = 0; i < 4; i++)
      a[i] = *(const short8*)(Rc + ((i * 16 + ln) * 4 + (quad ^ qsw)) * 8);
#pragma unroll
    for (int j = 0; j < 4; j++)
      b[j] = *(const short8*)(Rc + 2048 + ((wn + j * 16 + ln) * 4 + (quad ^ qsw)) * 8);
    __builtin_amdgcn_s_setprio(1);
#pragma unroll
    for (int i = 0; i < 4; i++)
#pragma unroll
      for (int j = 0; j < 4; j++)
        acc[i][j] = __builtin_amdgcn_mfma_f32_16x16x32_bf16(b[j], a[i], acc[i][j], 0, 0, 0);
    __builtin_amdgcn_s_setprio(0);
    // issue step kti+2 (ring[(kti+2)%3] last read iter kti-1; barrier separates)
    if (kti + 2 < nk) {
      const int kt = (kti + 2) * 32;
      u16* Rn = &ring[(kti + 2) % 3][0];
      const int row = tid >> 2;
      const int c = (tid & 3) ^ ((row >> 1) & 3);
      __builtin_amdgcn_global_load_lds(
          (AS1C)(Ab + (size_t)row * K + kt + c * 8), (AS3P)(Rn + tid * 8), 16, 0, 0);
#pragma unroll
      for (int p = 0; p < 4; p++) {
        const int s = p * 256 + tid;
        const int br = s >> 2;
        const int bc = (s & 3) ^ ((br >> 1) & 3);
        __builtin_amdgcn_global_load_lds(
            (AS1C)(BT + (size_t)br * K + kt + bc * 8), (AS3P)(Rn + 2048 + s * 8), 16, 0, 0);
      }
    }
  }

  // ---- epilogue: v = acc + bias + resid; LayerNorm over the 256-row ----
#pragma unroll
  for (int i = 0; i < 4; i++) {
    const long gm = bm + i * 16 + ln;
    float s = 0.f, q = 0.f;
#pragma unroll
    for (int j = 0; j < 4; j++) {
      const int n0 = wn + j * 16 + quad * 4;
      const float4 b4 = *(const float4*)(bias + n0);
      const ushort4 r4 = *(const ushort4*)(residb + (size_t)gm * 256 + n0);
      acc[i][j][0] += b4.x + b2f(r4.x);
      acc[i][j][1] += b4.y + b2f(r4.y);
      acc[i][j][2] += b4.z + b2f(r4.z);
      acc[i][j][3] += b4.w + b2f(r4.w);
#pragma unroll
      for (int r = 0; r < 4; r++) { s += acc[i][j][r]; q += acc[i][j][r] * acc[i][j][r]; }
    }
    s += __shfl_xor(s, 16); s += __shfl_xor(s, 32);
    q += __shfl_xor(q, 16); q += __shfl_xor(q, 32);
    if (quad == 0) { redS[wid][i * 16 + ln] = s; redQ[wid][i * 16 + ln] = q; }
  }
  __syncthreads();
#pragma unroll
  for (int i = 0; i < 4; i++) {
    const long gm = bm + i * 16 + ln;
    float s = 0.f, q = 0.f;
#pragma unroll
    for (int w = 0; w < 4; w++) { s += redS[w][i * 16 + ln]; q += redQ[w][i * 16 + ln]; }
    const float mu = s * (1.f / 256.f);
    const float inv = rsqrtf(q * (1.f / 256.f) - mu * mu + 1e-3f);
#pragma unroll
    for (int j = 0; j < 4; j++) {
      const int n0 = wn + j * 16 + quad * 4;
      const float4 gg = *(const float4*)(g + n0);
      const float4 bb = *(const float4*)(beta + n0);
      float o0 = (acc[i][j][0] - mu) * inv * gg.x + bb.x;
      float o1 = (acc[i][j][1] - mu) * inv * gg.y + bb.y;
      float o2 = (acc[i][j][2] - mu) * inv * gg.z + bb.z;
      float o3 = (acc[i][j][3] - mu) * inv * gg.w + bb.w;
      const size_t off = (size_t)gm * 256 + n0;
      if (yout) {
        float4 o4; o4.x = o0; o4.y = o1; o4.z = o2; o4.w = o3;
        *(float4*)(yout + off) = o4;
      }
      if (ybout) {
        ushort4 ob;
        ob.x = f2b(o0); ob.y = f2b(o1); ob.z = f2b(o2); ob.w = f2b(o3);
        *(ushort4*)(ybout + off) = ob;
      }
    }
  }
}

// ---------------------------------------------------------------------------
extern "C" void kernel_launch(void* const* d_in, const int* in_sizes, int n_in,
                              void* d_out, int out_size, void* d_ws, size_t ws_size,
                              hipStream_t stream) {
  (void)in_sizes; (void)n_in; (void)out_size; (void)ws_size;
  const float* x    = (const float*)d_in[0];
  const float* Wq   = (const float*)d_in[1];
  const float* bq   = (const float*)d_in[2];
  const float* Wk   = (const float*)d_in[3];
  const float* bk   = (const float*)d_in[4];
  const float* Wv   = (const float*)d_in[5];
  const float* bv   = (const float*)d_in[6];
  const float* Wo   = (const float*)d_in[7];
  const float* bo   = (const float*)d_in[8];
  const float* ln1g = (const float*)d_in[9];
  const float* ln1b = (const float*)d_in[10];
  const float* W1   = (const float*)d_in[11];
  const float* b1   = (const float*)d_in[12];
  const float* W2   = (const float*)d_in[13];
  const float* b2   = (const float*)d_in[14];
  const float* ln2g = (const float*)d_in[15];
  const float* ln2b = (const float*)d_in[16];
  float* out = (float*)d_out;

  char* ws = (char*)d_ws;
  u16*   WQKVT = (u16*)(ws + OFF_WQKVT);
  u16*   WOT   = (u16*)(ws + OFF_WOT);
  u16*   W1T   = (u16*)(ws + OFF_W1T);
  u16*   W2T   = (u16*)(ws + OFF_W2T);
  float* BQKV  = (float*)(ws + OFF_BQKV);
  u16*   XB    = (u16*)(ws + OFF_XB);
  u16*   QKV   = (u16*)(ws + OFF_QKV);
  u16*   YB    = (u16*)(ws + OFF_YB);
  u16*   HB    = (u16*)(ws + OFF_HB);
  u16*   VT    = (u16*)(ws + OFF_VT);
  u16*   CTX   = (u16*)(ws + OFF_CTX);

  // cast_x (8192 blocks) + prep_w (257 blocks) merged: prep hides in cast
  cast_prep_kernel<<<8449, 256, 0, stream>>>(x, XB, Wq, Wk, Wv, Wo, W1, W2,
                                             bq, bk, bv, WQKVT, WOT, W1T, W2T, BQKV);
  // QKV projection (128-col panels, 512-row m-chunks): Q,K -> QKV; V -> VT
  gemm_nres<<<768, 256, 0, stream>>>(XB, WQKVT, BQKV, QKV, VT, 1536, 1024, 0);
  // Fused attention v6 (final)
  attn_fused<<<1024, 512, 0, stream>>>(QKV, VT, CTX);
  // attn-out projection + residual(XB) + LN1 -> YB (bf16)
  gemm_ln<<<512, 256, 0, stream>>>(CTX, WOT, bo, XB, ln1g, ln1b, nullptr, YB, 512);
  // FF1 + ReLU (128-col panels): [32768,256] x [256,1024]
  gemm_nres<<<512, 256, 0, stream>>>(YB, W1T, b1, HB, nullptr, 1024, 1 << 30, 1);
  // FF2 + residual(YB) + LN2 -> out (f32)
  gemm_ln<<<512, 256, 0, stream>>>(HB, W2T, b2, YB, ln2g, ln2b, out, nullptr, 1024);
}